// Round 14
// baseline (162.146 us; speedup 1.0000x reference)
//
#include <hip/hip_runtime.h>
#include <hip/hip_bf16.h>

#define NROWS 131072
#define DK    1024
#define CCLS  21
#define CTF   84
#define NCOL  105          // 21 + 84
#define NCT   7            // 112 padded cols / 16
#define BM    16           // rows per block = one MFMA row-tile
#define SLABF 128          // f32 of K per slab -> 4 k-tiles, 1 per wave
#define NSLAB (DK / SLABF) // 8

typedef __attribute__((ext_vector_type(4))) float f32x4;
typedef __attribute__((ext_vector_type(8))) short bf16x8;
typedef __attribute__((ext_vector_type(2))) unsigned int u32x2;

__device__ __forceinline__ unsigned short f2bf_rne(float x) {
    union { float f; unsigned u; } v; v.f = x;
    unsigned r = v.u + 0x7fffu + ((v.u >> 16) & 1u);
    return (unsigned short)(r >> 16);
}

__device__ __forceinline__ unsigned pack2(float lo, float hi) {
    union { float f; unsigned u; } a, b; a.f = lo; b.f = hi;
    return ((a.u + 0x8000u) >> 16) | ((b.u + 0x8000u) & 0xffff0000u);
}

// Pack [W_cls | W_tf | zero-pad] into bf16 MFMA B-fragment order (verified):
// element ((kt*NCT+ct)*64+lane)*8 + j = B[k][col],
// col = ct*16 + (lane&15), k = kt*32 + (lane>>4)*8 + j
__global__ void pack_B_kernel(const float* __restrict__ Wc,
                              const float* __restrict__ Wt,
                              unsigned short* __restrict__ Bp) {
    const int frag = blockIdx.x;           // 224 total
    const int kt = frag / NCT, ct = frag % NCT;
    const int lane = threadIdx.x;          // 64
    const int col = ct * 16 + (lane & 15);
    const int k0  = kt * 32 + ((lane >> 4) << 3);
    bf16x8 o;
#pragma unroll
    for (int j = 0; j < 8; ++j) {
        const int k = k0 + j;
        float v = 0.0f;
        if (col < CCLS)      v = Wc[k * CCLS + col];
        else if (col < NCOL) v = Wt[k * CTF + (col - CCLS)];
        o[j] = (short)f2bf_rne(v);
    }
    *reinterpret_cast<bf16x8*>(Bp + ((size_t)frag * 64 + lane) * 8) = o;
}

// Depth-2 zero-stall pipeline: per slab issue [B(s+1)][A(s+2)], compute(s)
// on loads issued one full slab earlier (all waits counted & satisfied),
// write tile s+1, raw s_barrier with lgkm-only wait (VMEM stays in flight
// across barriers). Reg-staged VGPR loads (probe-proven path); XOR-swizzled
// LDS both sides; K-split across 4 waves; LDS reduce epilogue (R13-verified).
__global__ __launch_bounds__(256, 4)
void roi_gemm_kernel(const float* __restrict__ F,
                     const unsigned short* __restrict__ Bp,
                     const float* __restrict__ bcls,
                     const float* __restrict__ btf,
                     float* __restrict__ out) {
    // 2 bufs x 16 rows x 256B bf16 = 8 KB staging; reduce overlay = 28 KB
    __shared__ __align__(16) unsigned char smem[28672];

    const int t    = threadIdx.x;
    const int wave = t >> 6;
    const int lane = t & 63;
    const int fr   = lane & 15;      // A row-in-tile / B col
    const int fq   = lane >> 4;      // 0..3
    const long rw  = (long)blockIdx.x * BM;

    const unsigned short* bb = Bp + (size_t)lane * 8;
    // A load q covers rows {wave*4+2q, wave*4+2q+1} (lane>>5 picks row),
    // 32 lanes x 16B = 512B = one row-slab. Source col f32 = (lane&31)*4.
    const float* asrc = F + (size_t)(rw + wave * 4 + (lane >> 5)) * DK
                        + (lane & 31) * 4;

    // LDS byte offsets (row-slab = 256B, 16B-chunk XOR swizzle by row&7):
    const int c   = (lane & 31) >> 1;               // write chunk
    const int h8  = (lane & 1) << 3;                // write half
    const int R0  = wave * 4 + (lane >> 5);
    const int R1  = R0 + 2;
    const int w0  = R0 * 256 + (((c) ^ (R0 & 7)) << 4) + h8;
    const int w1  = R1 * 256 + (((c) ^ (R1 & 7)) << 4) + h8;
    const int rdoff = fr * 256 + (((wave * 4 + fq) ^ (fr & 7)) << 4);

    f32x4 acc[NCT];
#pragma unroll
    for (int ct = 0; ct < NCT; ++ct) acc[ct] = (f32x4){0.f, 0.f, 0.f, 0.f};

    f32x4 vP[2], vQ[2];
    bf16x8 bfrP[NCT], bfrQ[NCT];

#define LOADA(V, S) do {                                                      \
    V[0] = *reinterpret_cast<const f32x4*>(asrc + (size_t)(S) * SLABF);       \
    V[1] = *reinterpret_cast<const f32x4*>(asrc + (size_t)(S) * SLABF         \
                                           + 2 * DK);                         \
} while (0)

#define LOADB(BF, S) do {                                                     \
    const int ktg_ = (S) * 4 + wave;                                          \
    _Pragma("unroll")                                                         \
    for (int ct = 0; ct < NCT; ++ct)                                          \
        BF[ct] = *reinterpret_cast<const bf16x8*>(                            \
            bb + ((size_t)(ktg_ * NCT + ct) * 512));                          \
} while (0)

#define WRITEA(V, BUF) do {                                                   \
    u32x2 d0_; d0_[0] = pack2(V[0][0], V[0][1]);                              \
    d0_[1] = pack2(V[0][2], V[0][3]);                                         \
    u32x2 d1_; d1_[0] = pack2(V[1][0], V[1][1]);                              \
    d1_[1] = pack2(V[1][2], V[1][3]);                                         \
    *reinterpret_cast<u32x2*>(smem + (BUF) * 4096 + w0) = d0_;                \
    *reinterpret_cast<u32x2*>(smem + (BUF) * 4096 + w1) = d1_;                \
} while (0)

#define COMPUTE(BF, BUF) do {                                                 \
    const bf16x8 a_ = *reinterpret_cast<const bf16x8*>(                       \
        smem + (BUF) * 4096 + rdoff);                                         \
    _Pragma("unroll")                                                         \
    for (int ct = 0; ct < NCT; ++ct)                                          \
        acc[ct] = __builtin_amdgcn_mfma_f32_16x16x32_bf16(                    \
            a_, BF[ct], acc[ct], 0, 0, 0);                                    \
} while (0)

#define SLAB(S, BCUR, BNXT, VW, VL) do {                                      \
    if ((S) + 1 < NSLAB) LOADB(BNXT, (S) + 1);                                \
    __builtin_amdgcn_sched_barrier(0);                                        \
    if ((S) + 2 < NSLAB) LOADA(VL, (S) + 2);                                  \
    __builtin_amdgcn_sched_barrier(0);                                        \
    COMPUTE(BCUR, (S) & 1);                                                   \
    __builtin_amdgcn_sched_barrier(0);                                        \
    if ((S) + 1 < NSLAB) {                                                    \
        WRITEA(VW, ((S) + 1) & 1);                                            \
        __builtin_amdgcn_sched_barrier(0);                                    \
        asm volatile("s_waitcnt lgkmcnt(0)" ::: "memory");                    \
        __builtin_amdgcn_s_barrier();                                         \
        __builtin_amdgcn_sched_barrier(0);                                    \
    }                                                                         \
} while (0)

    // ---- prologue: A(0), A(1), B(0) in flight; publish tile 0
    LOADA(vP, 0);
    LOADA(vQ, 1);
    LOADB(bfrP, 0);
    __builtin_amdgcn_sched_barrier(0);
    WRITEA(vP, 0);             // counted wait retires A(0) only
    __builtin_amdgcn_sched_barrier(0);
    asm volatile("s_waitcnt lgkmcnt(0)" ::: "memory");
    __builtin_amdgcn_s_barrier();
    __builtin_amdgcn_sched_barrier(0);

    SLAB(0, bfrP, bfrQ, vQ, vP);
    SLAB(1, bfrQ, bfrP, vP, vQ);
    SLAB(2, bfrP, bfrQ, vQ, vP);
    SLAB(3, bfrQ, bfrP, vP, vQ);
    SLAB(4, bfrP, bfrQ, vQ, vP);
    SLAB(5, bfrQ, bfrP, vP, vQ);
    SLAB(6, bfrP, bfrQ, vQ, vP);
    SLAB(7, bfrQ, bfrP, vP, vQ);

#undef SLAB
#undef COMPUTE
#undef WRITEA
#undef LOADB
#undef LOADA

    // ---- cross-wave K reduction through LDS (overlay; R13-verified)
    __syncthreads();   // all waves done with tile bufs before overlay
    float* sf = reinterpret_cast<float*>(smem);
#pragma unroll
    for (int ct = 0; ct < NCT; ++ct)
        *reinterpret_cast<f32x4*>(sf + ((wave * NCT + ct) << 8) + (lane << 2)) =
            acc[ct];
    __syncthreads();

    // reduce 4 partials + bias + store (R13-verified):
    // slot f32 index t: col = ct*16 + ((t>>2)&15), Mrow = ((t>>6)<<2)+(t&3)
    const int rcol0 = (t >> 2) & 15;
    float* out_tf = out + (size_t)NROWS * CCLS;
    const long grow = rw + ((t >> 6) << 2) + (t & 3);
#pragma unroll
    for (int ct = 0; ct < NCT; ++ct) {
        const int col = ct * 16 + rcol0;
        if (col >= NCOL) continue;
        const float v = sf[(0 * NCT + ct) * 256 + t] +
                        sf[(1 * NCT + ct) * 256 + t] +
                        sf[(2 * NCT + ct) * 256 + t] +
                        sf[(3 * NCT + ct) * 256 + t] +
                        ((col < CCLS) ? bcls[col] : btf[col - CCLS]);
        if (col < CCLS) out[grow * CCLS + col] = v;
        else            out_tf[grow * CTF + (col - CCLS)] = v;
    }
}

extern "C" void kernel_launch(void* const* d_in, const int* in_sizes, int n_in,
                              void* d_out, int out_size, void* d_ws, size_t ws_size,
                              hipStream_t stream) {
    const float* F  = (const float*)d_in[0];
    const float* Wc = (const float*)d_in[1];
    const float* bc = (const float*)d_in[2];
    const float* Wt = (const float*)d_in[3];
    const float* bt = (const float*)d_in[4];
    unsigned short* Bp = (unsigned short*)d_ws;   // 229,376 B

    pack_B_kernel<<<NCT * (DK / 32), 64, 0, stream>>>(Wc, Wt, Bp);
    roi_gemm_kernel<<<NROWS / BM, 256, 0, stream>>>(F, Bp, bc, bt,
                                                    (float*)d_out);
}

// Round 15
// 151.799 us; speedup vs baseline: 1.0682x; 1.0682x over previous
//
#include <hip/hip_runtime.h>
#include <hip/hip_bf16.h>

#define NROWS 131072
#define DK    1024
#define CCLS  21
#define CTF   84
#define NCOL  105          // 21 + 84
#define NCT   7            // 112 padded cols / 16
#define BM    16           // rows per block = one MFMA row-tile
#define SLABF 256          // f32 of K per slab = 1KB/row, 8 k-tiles/slab
#define NSLAB (DK / SLABF) // 4

typedef __attribute__((ext_vector_type(4))) float f32x4;
typedef __attribute__((ext_vector_type(8))) short bf16x8;
typedef __attribute__((ext_vector_type(2))) unsigned int u32x2;

__device__ __forceinline__ unsigned short f2bf_rne(float x) {
    union { float f; unsigned u; } v; v.f = x;
    unsigned r = v.u + 0x7fffu + ((v.u >> 16) & 1u);
    return (unsigned short)(r >> 16);
}

__device__ __forceinline__ unsigned pack2(float lo, float hi) {
    union { float f; unsigned u; } a, b; a.f = lo; b.f = hi;
    return ((a.u + 0x8000u) >> 16) | ((b.u + 0x8000u) & 0xffff0000u);
}

// Pack [W_cls | W_tf | zero-pad] into bf16 MFMA B-fragment order (verified):
// element ((kt*NCT+ct)*64+lane)*8 + j = B[k][col],
// col = ct*16 + (lane&15), k = kt*32 + (lane>>4)*8 + j
__global__ void pack_B_kernel(const float* __restrict__ Wc,
                              const float* __restrict__ Wt,
                              unsigned short* __restrict__ Bp) {
    const int frag = blockIdx.x;           // 224 total
    const int kt = frag / NCT, ct = frag % NCT;
    const int lane = threadIdx.x;          // 64
    const int col = ct * 16 + (lane & 15);
    const int k0  = kt * 32 + ((lane >> 4) << 3);
    bf16x8 o;
#pragma unroll
    for (int j = 0; j < 8; ++j) {
        const int k = k0 + j;
        float v = 0.0f;
        if (col < CCLS)      v = Wc[k * CCLS + col];
        else if (col < NCOL) v = Wt[k * CTF + (col - CCLS)];
        o[j] = (short)f2bf_rne(v);
    }
    *reinterpret_cast<bf16x8*>(Bp + ((size_t)frag * 64 + lane) * 8) = o;
}

// R13 + {raw lgkm-only barriers (loads live across barriers), A depth-2}.
// Per slab: [B(s) x14][A(s+2) x4][compute(s)][ds_write A(s+1)][lgkm+s_barrier].
// FIFO: compute's B-wait retires only loads >= 1 slab old + B itself; the
// write's A-wait is always satisfied (issued a full slab earlier). No
// vmcnt(0) anywhere in the loop. 1KB-contiguous A loads (R13-verified).
__global__ __launch_bounds__(256, 3)
void roi_gemm_kernel(const float* __restrict__ F,
                     const unsigned short* __restrict__ Bp,
                     const float* __restrict__ bcls,
                     const float* __restrict__ btf,
                     float* __restrict__ out) {
    // staging: 2 bufs x 16 rows x 512B bf16 = 16 KB; reduce overlay = 28 KB
    __shared__ __align__(16) unsigned char smem[28672];

    const int t    = threadIdx.x;
    const int wave = t >> 6;
    const int lane = t & 63;
    const int fr   = lane & 15;      // A row-in-tile / B col
    const int fq   = lane >> 4;      // 0..3
    const long rw  = (long)blockIdx.x * BM;

    const unsigned short* bb = Bp + (size_t)lane * 8;
    // wave stages rows wave*4..wave*4+3; one inst = 1KB contiguous of 1 row
    const float* asrc = F + (size_t)(rw + wave * 4) * DK + lane * 4;

    f32x4 acc[NCT];
#pragma unroll
    for (int ct = 0; ct < NCT; ++ct) acc[ct] = (f32x4){0.f, 0.f, 0.f, 0.f};

    f32x4 vP[4], vQ[4];
    bf16x8 bfr0[NCT], bfr1[NCT];

#define SB __builtin_amdgcn_sched_barrier(0)

#define LOADA(V, S) do {                                                      \
    _Pragma("unroll")                                                         \
    for (int q = 0; q < 4; ++q)                                               \
        V[q] = *reinterpret_cast<const f32x4*>(                               \
            asrc + (size_t)q * DK + (size_t)(S) * SLABF);                     \
} while (0)

#define LOADB(BF, S, JJ) do {                                                 \
    const int ktg_ = (S) * 8 + wave * 2 + (JJ);                               \
    _Pragma("unroll")                                                         \
    for (int ct = 0; ct < NCT; ++ct)                                          \
        BF[ct] = *reinterpret_cast<const bf16x8*>(                            \
            bb + ((size_t)(ktg_ * NCT + ct) * 512));                          \
} while (0)

// write row R=wave*4+q of buffer BUF (R13-verified swizzle)
#define WRITEA(V, BUF) do {                                                   \
    _Pragma("unroll")                                                         \
    for (int q = 0; q < 4; ++q) {                                             \
        const int R_ = wave * 4 + q;                                          \
        u32x2 d_;                                                             \
        d_[0] = pack2(V[q][0], V[q][1]);                                      \
        d_[1] = pack2(V[q][2], V[q][3]);                                      \
        *reinterpret_cast<u32x2*>(smem + (BUF) * 8192 + R_ * 512 +            \
            (((lane >> 1) ^ (R_ & 7)) << 4) + ((lane & 1) << 3)) = d_;        \
    }                                                                         \
} while (0)

#define COMPUTE(BF, BUF, JJ) do {                                             \
    const int lt_ = wave * 2 + (JJ);                                          \
    const bf16x8 a_ = *reinterpret_cast<const bf16x8*>(                       \
        smem + (BUF) * 8192 + fr * 512 +                                      \
        ((((lt_ << 2) | fq) ^ (fr & 7)) << 4));                               \
    _Pragma("unroll")                                                         \
    for (int ct = 0; ct < NCT; ++ct)                                          \
        acc[ct] = __builtin_amdgcn_mfma_f32_16x16x32_bf16(                    \
            a_, BF[ct], acc[ct], 0, 0, 0);                                    \
} while (0)

#define SLAB(S, VL, VW) do {                                                  \
    LOADB(bfr0, S, 0);                                                        \
    LOADB(bfr1, S, 1);                                                        \
    SB;                                                                       \
    if ((S) + 2 < NSLAB) { LOADA(VL, (S) + 2); }                              \
    SB;                                                                       \
    COMPUTE(bfr0, (S) & 1, 0);                                                \
    COMPUTE(bfr1, (S) & 1, 1);                                                \
    SB;                                                                       \
    if ((S) + 1 < NSLAB) {                                                    \
        WRITEA(VW, ((S) + 1) & 1);                                            \
        SB;                                                                   \
        asm volatile("s_waitcnt lgkmcnt(0)" ::: "memory");                    \
        __builtin_amdgcn_s_barrier();                                         \
        SB;                                                                   \
    }                                                                         \
} while (0)

    // ---- prologue: A(0)->vP, A(1)->vQ in flight; publish tile 0
    LOADA(vP, 0);
    LOADA(vQ, 1);
    SB;
    WRITEA(vP, 0);             // counted wait retires A(0) only, A(1) flies
    SB;
    asm volatile("s_waitcnt lgkmcnt(0)" ::: "memory");
    __builtin_amdgcn_s_barrier();
    SB;

    // rotation: A(2)->vP @s0, A(3)->vQ @s1; writes: A(1)=vQ @s0,
    // A(2)=vP @s1, A(3)=vQ @s2.
    SLAB(0, vP, vQ);
    SLAB(1, vQ, vP);
    SLAB(2, vP, vQ);   // VL unused (S+2>=NSLAB)
    SLAB(3, vP, vQ);   // VL/VW unused

#undef SLAB
#undef COMPUTE
#undef WRITEA
#undef LOADB
#undef LOADA
#undef SB

    // ---- cross-wave K reduction through LDS (overlay; R13-verified)
    __syncthreads();   // all waves done with tile bufs before overlay
    float* sf = reinterpret_cast<float*>(smem);
#pragma unroll
    for (int ct = 0; ct < NCT; ++ct)
        *reinterpret_cast<f32x4*>(sf + ((wave * NCT + ct) << 8) + (lane << 2)) =
            acc[ct];
    __syncthreads();

    // reduce 4 partials + bias + store (R13-verified):
    // slot f32 index t: col = ct*16 + ((t>>2)&15), Mrow = ((t>>6)<<2)+(t&3)
    const int rcol0 = (t >> 2) & 15;
    float* out_tf = out + (size_t)NROWS * CCLS;
    const long grow = rw + ((t >> 6) << 2) + (t & 3);
#pragma unroll
    for (int ct = 0; ct < NCT; ++ct) {
        const int col = ct * 16 + rcol0;
        if (col >= NCOL) continue;
        const float v = sf[(0 * NCT + ct) * 256 + t] +
                        sf[(1 * NCT + ct) * 256 + t] +
                        sf[(2 * NCT + ct) * 256 + t] +
                        sf[(3 * NCT + ct) * 256 + t] +
                        ((col < CCLS) ? bcls[col] : btf[col - CCLS]);
        if (col < CCLS) out[grow * CCLS + col] = v;
        else            out_tf[grow * CTF + (col - CCLS)] = v;
    }
}

extern "C" void kernel_launch(void* const* d_in, const int* in_sizes, int n_in,
                              void* d_out, int out_size, void* d_ws, size_t ws_size,
                              hipStream_t stream) {
    const float* F  = (const float*)d_in[0];
    const float* Wc = (const float*)d_in[1];
    const float* bc = (const float*)d_in[2];
    const float* Wt = (const float*)d_in[3];
    const float* bt = (const float*)d_in[4];
    unsigned short* Bp = (unsigned short*)d_ws;   // 229,376 B

    pack_B_kernel<<<NCT * (DK / 32), 64, 0, stream>>>(Wc, Wt, Bp);
    roi_gemm_kernel<<<NROWS / BM, 256, 0, stream>>>(F, Bp, bc, bt,
                                                    (float*)d_out);
}

// Round 16
// 145.146 us; speedup vs baseline: 1.1171x; 1.0458x over previous
//
#include <hip/hip_runtime.h>
#include <hip/hip_bf16.h>

#define NROWS 131072
#define DK    1024
#define CCLS  21
#define CTF   84
#define NCOL  105          // 21 + 84
#define NCT   7            // 112 padded cols / 16
#define BM    16           // rows per block = one MFMA row-tile
#define SLABF 256          // f32 per row per slab = 1KB contiguous per load
#define NSLAB (DK / SLABF) // 4

typedef __attribute__((ext_vector_type(4))) float f32x4;
typedef __attribute__((ext_vector_type(8))) short bf16x8;
typedef __attribute__((ext_vector_type(2))) unsigned int u32x2;

__device__ __forceinline__ unsigned short f2bf_rne(float x) {
    union { float f; unsigned u; } v; v.f = x;
    unsigned r = v.u + 0x7fffu + ((v.u >> 16) & 1u);
    return (unsigned short)(r >> 16);
}

__device__ __forceinline__ unsigned pack2(float lo, float hi) {
    union { float f; unsigned u; } a, b; a.f = lo; b.f = hi;
    return ((a.u + 0x8000u) >> 16) | ((b.u + 0x8000u) & 0xffff0000u);
}

// Pack [W_cls | W_tf | zero-pad] into bf16 MFMA B-fragment order (verified):
// element ((kt*NCT+ct)*64+lane)*8 + j = B[k][col],
// col = ct*16 + (lane&15), k = kt*32 + (lane>>4)*8 + j
__global__ void pack_B_kernel(const float* __restrict__ Wc,
                              const float* __restrict__ Wt,
                              unsigned short* __restrict__ Bp) {
    const int frag = blockIdx.x;           // 224 total
    const int kt = frag / NCT, ct = frag % NCT;
    const int lane = threadIdx.x;          // 64
    const int col = ct * 16 + (lane & 15);
    const int k0  = kt * 32 + ((lane >> 4) << 3);
    bf16x8 o;
#pragma unroll
    for (int j = 0; j < 8; ++j) {
        const int k = k0 + j;
        float v = 0.0f;
        if (col < CCLS)      v = Wc[k * CCLS + col];
        else if (col < NCOL) v = Wt[k * CTF + (col - CCLS)];
        o[j] = (short)f2bf_rne(v);
    }
    *reinterpret_cast<bf16x8*>(Bp + ((size_t)frag * 64 + lane) * 8) = o;
}

// R13 (measured best, 145.1 us): reg-staged GEMM with FIFO-correct prefetch.
// Per slab, issue order is [B x14][A(s+1) x4] so compute's B-waits retire
// ONLY B (vmcnt FIFO) and the A prefetch stays in flight through compute +
// write. VGPR loads (probe-proven 6.3 TB/s path), 1KB contiguous per
// instruction. XOR-swizzled LDS on both write and read sides.
__global__ __launch_bounds__(256, 4)
void roi_gemm_kernel(const float* __restrict__ F,
                     const unsigned short* __restrict__ Bp,
                     const float* __restrict__ bcls,
                     const float* __restrict__ btf,
                     float* __restrict__ out) {
    // staging: 2 bufs x 16 rows x 512B bf16 = 16 KB; reduce overlay = 28 KB
    __shared__ __align__(16) unsigned char smem[28672];

    const int t    = threadIdx.x;
    const int wave = t >> 6;
    const int lane = t & 63;
    const int fr   = lane & 15;      // A row-in-tile / B col
    const int fq   = lane >> 4;      // 0..3
    const long rw  = (long)blockIdx.x * BM;

    const unsigned short* bb = Bp + (size_t)lane * 8;
    // wave stages rows wave*4..wave*4+3; lane covers 16B at col lane*4
    const float* abase = F + (size_t)(rw + wave * 4) * DK + lane * 4;

    f32x4 acc[NCT];
#pragma unroll
    for (int ct = 0; ct < NCT; ++ct) acc[ct] = (f32x4){0.f, 0.f, 0.f, 0.f};

    // LDS addresses (bf16 tile, 512B/row, 16B-chunk XOR swizzle by row&7):
    //  write row R=wave*4+q: byte = buf*8192 + R*512
    //        + (((lane>>1) ^ (R&7))<<4) + ((lane&1)<<3)
    //  read  k-tile lt:      byte = buf*8192 + fr*512
    //        + ((((lt<<2)|fq) ^ (fr&7))<<4)
#define AWADDR(BUF, Q) (smem + (BUF) * 8192 + (wave * 4 + (Q)) * 512 +        \
    (((lane >> 1) ^ ((wave * 4 + (Q)) & 7)) << 4) + ((lane & 1) << 3))

    // ---- prologue: load + write slab 0
    {
        f32x4 v0[4];
#pragma unroll
        for (int q = 0; q < 4; ++q)
            v0[q] = *reinterpret_cast<const f32x4*>(abase + (size_t)q * DK);
#pragma unroll
        for (int q = 0; q < 4; ++q) {
            u32x2 d;
            d[0] = pack2(v0[q][0], v0[q][1]);
            d[1] = pack2(v0[q][2], v0[q][3]);
            *reinterpret_cast<u32x2*>(AWADDR(0, q)) = d;
        }
    }
    __syncthreads();

#pragma unroll
    for (int s = 0; s < NSLAB; ++s) {
        const int buf = s & 1;

        // [1] ALL B-fragment loads for slab s — FIRST in the VMEM FIFO
        bf16x8 bfr[2][NCT];
#pragma unroll
        for (int jj = 0; jj < 2; ++jj) {
            const int ktg = s * 8 + wave * 2 + jj;
#pragma unroll
            for (int ct = 0; ct < NCT; ++ct)
                bfr[jj][ct] = *reinterpret_cast<const bf16x8*>(
                    bb + ((size_t)(ktg * NCT + ct) * 512));
        }
        __builtin_amdgcn_sched_barrier(0);

        // [2] A prefetch for slab s+1 — AFTER B, so B-waits keep it in flight
        f32x4 v[4];
        if (s + 1 < NSLAB) {
#pragma unroll
            for (int q = 0; q < 4; ++q)
                v[q] = *reinterpret_cast<const f32x4*>(
                    abase + (size_t)q * DK + (s + 1) * SLABF);
        }
        __builtin_amdgcn_sched_barrier(0);

        // [3] compute slab s (B-waits are counted: vmcnt retires only B)
#pragma unroll
        for (int jj = 0; jj < 2; ++jj) {
            const int lt = wave * 2 + jj;
            const bf16x8 a = *reinterpret_cast<const bf16x8*>(
                smem + buf * 8192 + fr * 512 +
                ((((lt << 2) | fq) ^ (fr & 7)) << 4));
#pragma unroll
            for (int ct = 0; ct < NCT; ++ct)
                acc[ct] = __builtin_amdgcn_mfma_f32_16x16x32_bf16(
                    a, bfr[jj][ct], acc[ct], 0, 0, 0);
        }
        __builtin_amdgcn_sched_barrier(0);

        // [4] cvt + write slab s+1 into the other buffer (A-wait lands here)
        if (s + 1 < NSLAB) {
#pragma unroll
            for (int q = 0; q < 4; ++q) {
                u32x2 d;
                d[0] = pack2(v[q][0], v[q][1]);
                d[1] = pack2(v[q][2], v[q][3]);
                *reinterpret_cast<u32x2*>(AWADDR(buf ^ 1, q)) = d;
            }
        }
        __syncthreads();   // publish slab s+1 (outstanding VMEM is 0 here)
    }
#undef AWADDR

    // ---- cross-wave K reduction through LDS (overlay; verified in R12)
    float* sf = reinterpret_cast<float*>(smem);
#pragma unroll
    for (int ct = 0; ct < NCT; ++ct)
        *reinterpret_cast<f32x4*>(sf + ((wave * NCT + ct) << 8) + (lane << 2)) =
            acc[ct];
    __syncthreads();

    // reduce 4 partials + bias + store (verified in R12):
    // slot f32 index t: col = ct*16 + ((t>>2)&15), Mrow = ((t>>6)<<2)+(t&3)
    const int rcol0 = (t >> 2) & 15;
    float* out_tf = out + (size_t)NROWS * CCLS;
    const long grow = rw + ((t >> 6) << 2) + (t & 3);
#pragma unroll
    for (int ct = 0; ct < NCT; ++ct) {
        const int col = ct * 16 + rcol0;
        if (col >= NCOL) continue;
        const float v = sf[(0 * NCT + ct) * 256 + t] +
                        sf[(1 * NCT + ct) * 256 + t] +
                        sf[(2 * NCT + ct) * 256 + t] +
                        sf[(3 * NCT + ct) * 256 + t] +
                        ((col < CCLS) ? bcls[col] : btf[col - CCLS]);
        if (col < CCLS) out[grow * CCLS + col] = v;
        else            out_tf[grow * CTF + (col - CCLS)] = v;
    }
}

extern "C" void kernel_launch(void* const* d_in, const int* in_sizes, int n_in,
                              void* d_out, int out_size, void* d_ws, size_t ws_size,
                              hipStream_t stream) {
    const float* F  = (const float*)d_in[0];
    const float* Wc = (const float*)d_in[1];
    const float* bc = (const float*)d_in[2];
    const float* Wt = (const float*)d_in[3];
    const float* bt = (const float*)d_in[4];
    unsigned short* Bp = (unsigned short*)d_ws;   // 229,376 B

    pack_B_kernel<<<NCT * (DK / 32), 64, 0, stream>>>(Wc, Wt, Bp);
    roi_gemm_kernel<<<NROWS / BM, 256, 0, stream>>>(F, Bp, bc, bt,
                                                    (float*)d_out);
}